// Round 18
// baseline (260.966 us; speedup 1.0000x reference)
//
#include <hip/hip_runtime.h>
#include <hip/hip_bf16.h>
#include <cstdint>

// Problem constants
#define BB  8
#define CH  64
#define TT  4096
#define KNN 9
#define NEG_INF (-3.402823466e38f)
#define SLOTS 96          // candidate bucket per row (2 halves, insert2 θ looser)
#define SSTR  97          // padded LDS stride (odd -> conflict-free scans)
#define KTH   12          // θ = 12th largest of per-(row,half) lane-union

typedef short  s16x8 __attribute__((ext_vector_type(8)));   // 8 bf16 MFMA frag
typedef float  f32x4 __attribute__((ext_vector_type(4)));   // MFMA acc

// Workspace layout (float units) — end 16,060,416 floats = 64.2 MB
constexpr size_t OFF_UB  = 0;                                  // u bf16 [B][9][T][C] ushort
constexpr size_t OFF_QTF = (size_t)BB*KNN*TT*CH/2;             //  9,437,184 qhatT f32 [B][T][C]
constexpr size_t OFF_KTF = OFF_QTF + (size_t)BB*TT*CH;         // 11,534,336 khatT f32
constexpr size_t OFF_QTB = OFF_KTF + (size_t)BB*TT*CH;         // 13,631,488 q bf16 FRAGMENT order
constexpr size_t OFF_KTB = OFF_QTB + (size_t)BB*TT*CH/2;       // 14,680,064 khatT bf16 row-major
constexpr size_t OFF_IDX = OFF_KTB + (size_t)BB*TT*CH/2;       // 15,728,640 (unused since r16)
constexpr size_t OFF_CWP = OFF_IDX + (size_t)BB*TT*KNN;        // 16,023,552 cwb bf16 frags (74KB)

__device__ __forceinline__ unsigned short f2bf(float f) {
    unsigned u = __float_as_uint(f);
    return (unsigned short)((u + 0x7FFFu + ((u >> 16) & 1u)) >> 16);
}

// value-only ascending top-2 (1 med3 + 1 max). s[0]=2nd largest, s[1]=largest.
__device__ __forceinline__ void insert2(float w, float (&s)[2]) {
    s[0] = __builtin_amdgcn_fmed3f(s[0], s[1], w);
    s[1] = fmaxf(s[1], w);
}

// θ = KTH-th largest of the union of the quad's 16 top-2 lists (destroys
// lists). Union ⊆ (row, half) values ⇒ θ ≤ half's KTH-th ≤ half's 9th
// (KTH=12 ≥ 9). Any row-global top-9 element in this half is within the
// half's top-9 ⇒ ≥ θ ⇒ collected in pass B. r14-proven.
__device__ __forceinline__ float popTheta2(float (&s)[2], int lane) {
    float theta = NEG_INF;
    #pragma unroll 1
    for (int p = 0; p < KTH; ++p) {
        float h = s[1];
        float m = h;
        m = fmaxf(m, __shfl_xor(m, 1));
        m = fmaxf(m, __shfl_xor(m, 2));
        m = fmaxf(m, __shfl_xor(m, 4));
        m = fmaxf(m, __shfl_xor(m, 8));
        unsigned long long bal = __ballot(h == m);
        unsigned qb = (unsigned)((bal >> (lane & 48)) & 0xFFFFull);
        int owner = __ffs(qb) - 1;
        if ((lane & 15) == owner) {
            s[1] = s[0]; s[0] = NEG_INF;
        }
        theta = m;
    }
    return theta;
}

// exact sorted-9 insert, value desc w/ index-asc tiebreak (final sort only)
__device__ __forceinline__ void insert9x(float w, int wi, float (&s)[9], int (&si)[9]) {
    bool c[9];
    #pragma unroll
    for (int k = 0; k < 9; ++k) c[k] = (w > s[k]) || (w == s[k] && wi < si[k]);
    #pragma unroll
    for (int k = 0; k < 8; ++k) si[k] = c[k + 1] ? si[k + 1] : (c[k] ? wi : si[k]);
    si[8] = c[8] ? wi : si[8];
    #pragma unroll
    for (int k = 0; k < 8; ++k) s[k] = c[k + 1] ? s[k + 1] : (c[k] ? w : s[k]);
    s[8] = c[8] ? w : s[8];
}

// ---------------------------------------------------------------------------
// K0: repack conv_w into bf16 MFMA B-FRAGMENT order:
//     cwb[((kk*4 + ot)*2 + ks)*64 + lane][i] = bf16(cw[o][cc*9 + kk])
//     with o = ot*16 + (lane&15), cc = ks*32 + (lane>>4)*8 + i.
// ---------------------------------------------------------------------------
__global__ void repack_cw_kernel(const float* __restrict__ cw, unsigned short* __restrict__ cwb) {
    int e = blockIdx.x * blockDim.x + threadIdx.x;      // (kk,ot,ks,lane)
    if (e >= KNN * 4 * 2 * 64) return;
    int lane = e & 63;
    int ks   = (e >> 6) & 1;
    int ot   = (e >> 7) & 3;
    int kk   = e >> 9;
    int o    = ot * 16 + (lane & 15);
    int cc0  = ks * 32 + (lane >> 4) * 8;
    unsigned short* dst = cwb + (size_t)e * 8;
    #pragma unroll
    for (int i = 0; i < 8; ++i)
        dst[i] = f2bf(cw[o * (CH * KNN) + (cc0 + i) * KNN + kk]);
}

// ---------------------------------------------------------------------------
// K1: QKV (fp32 VALU) + L2 normalize + q/k stores + u-projection on MFMA.
//     Round-18: *** grid 1024 (32-col tiles), 512 threads, d-split 16 ***.
//     Thread = (t = tid&31, dims d0 = (tid>>5)*4): per-thread QKV chain
//     halves again (768 fmaf); at ~48-64 VGPR the HW fits 4 blocks/CU =
//     32 waves/CU = 8 waves/SIMD (2x r17 TLP); LDS ~17KB doesn't bind.
//     u-proj: 8 waves -> (row-tile = w&1 of 32 rows, ot = w>>1), 18
//     MFMA/wave. All output layouts byte-identical to r17.
// ---------------------------------------------------------------------------
__global__ __launch_bounds__(512) void qkvu_kernel(
        const float* __restrict__ x,
        const float* __restrict__ Wq, const float* __restrict__ Wk, const float* __restrict__ Wv,
        const unsigned short* __restrict__ cwb,
        float* __restrict__ qtf, float* __restrict__ ktf,
        unsigned short* __restrict__ qtb, unsigned short* __restrict__ ktb,
        unsigned short* __restrict__ ub) {
    __shared__ __align__(16) float xs[CH * 32];
    __shared__ __align__(16) unsigned short vsb[32 * 64];   // v bf16, [t][cc]
    __shared__ float pq[16 * 32], pk[16 * 32];

    const int b   = blockIdx.x >> 7;
    const int tb  = blockIdx.x & 127;     // 32-col tile
    const int tid = threadIdx.x;

    const float* xb = x + ((size_t)b * CH) * TT + tb * 32;
    #pragma unroll
    for (int m = 0; m < 4; ++m) {
        int l = tid + 512 * m;
        xs[l] = xb[(size_t)(l >> 5) * TT + (l & 31)];
    }
    __syncthreads();

    const int t  = tid & 31;
    const int dg = __builtin_amdgcn_readfirstlane(tid >> 6) * 2 + ((tid >> 5) & 1); // 0..15
    const int d0 = dg * 4;

    float qa[4], ka[4], va[4];
    #pragma unroll
    for (int dd = 0; dd < 4; ++dd) { qa[dd] = 0.f; ka[dd] = 0.f; va[dd] = 0.f; }

    #pragma unroll 4
    for (int c = 0; c < CH; ++c) {
        float xv = xs[c * 32 + t];
        #pragma unroll
        for (int dd = 0; dd < 4; ++dd) {
            qa[dd] = fmaf(Wq[(d0 + dd) * CH + c], xv, qa[dd]);
            ka[dd] = fmaf(Wk[(d0 + dd) * CH + c], xv, ka[dd]);
            va[dd] = fmaf(Wv[(d0 + dd) * CH + c], xv, va[dd]);
        }
    }

    float sq = 0.f, sk = 0.f;
    #pragma unroll
    for (int dd = 0; dd < 4; ++dd) { sq = fmaf(qa[dd], qa[dd], sq); sk = fmaf(ka[dd], ka[dd], sk); }
    pq[dg * 32 + t] = sq;
    pk[dg * 32 + t] = sk;
    __syncthreads();

    float nq2 = 0.f, nk2 = 0.f;
    #pragma unroll
    for (int p = 0; p < 16; ++p) { nq2 += pq[p * 32 + t]; nk2 += pk[p * 32 + t]; }
    const float isq = 1.0f / fmaxf(sqrtf(nq2), 1e-12f);
    const float isk = 1.0f / fmaxf(sqrtf(nk2), 1e-12f);

    const size_t tg = (size_t)tb * 32 + t;
    float qn[4], kn[4];
    #pragma unroll
    for (int dd = 0; dd < 4; ++dd) {
        qn[dd] = qa[dd] * isq;
        kn[dd] = ka[dd] * isk;
    }
    // v bf16 transposed [t][cc]: thread owns cc = d0..d0+3 of row t (8B)
    {
        unsigned* vh = (unsigned*)&vsb[t * 64 + d0];
        vh[0] = (unsigned)f2bf(va[0]) | ((unsigned)f2bf(va[1]) << 16);
        vh[1] = (unsigned)f2bf(va[2]) | ((unsigned)f2bf(va[3]) << 16);
    }
    // q/k fp32 (one float4 each)
    *(float4*)(qtf + ((size_t)b * TT + tg) * CH + d0) = make_float4(qn[0], qn[1], qn[2], qn[3]);
    *(float4*)(ktf + ((size_t)b * TT + tg) * CH + d0) = make_float4(kn[0], kn[1], kn[2], kn[3]);
    // k bf16: row-major (8B)
    {
        unsigned* kh = (unsigned*)(ktb + ((size_t)b * TT + tg) * CH + d0);
        kh[0] = (unsigned)f2bf(kn[0]) | ((unsigned)f2bf(kn[1]) << 16);
        kh[1] = (unsigned)f2bf(kn[2]) | ((unsigned)f2bf(kn[3]) << 16);
    }
    // q bf16: FRAGMENT order — dims d0..d0+3 = half of 8-dim chunk g8 = dg>>1:
    // ks = g8>>2, quad = g8&3, in-chunk offset (dg&1)*4.
    {
        const int j0   = (int)(tg >> 4);
        const int l15q = (int)tg & 15;
        const int g8   = dg >> 1;
        const int ks   = g8 >> 2;
        const int qd   = g8 & 3;
        unsigned w0 = (unsigned)f2bf(qn[0]) | ((unsigned)f2bf(qn[1]) << 16);
        unsigned w1 = (unsigned)f2bf(qn[2]) | ((unsigned)f2bf(qn[3]) << 16);
        unsigned short* dst = qtb +
            ((((size_t)b * 256 + j0) * 2 + ks) * 64 + (qd * 16 + l15q)) * 8 + (dg & 1) * 4;
        *(uint2*)dst = make_uint2(w0, w1);
    }
    __syncthreads();

    // ---- u-projection via MFMA: u[t][o] = sum_cc v[t][cc] * cw[o][cc] ----
    // 8 waves: wave w -> row-tile rt = w&1 (rows rt*16..+15 of the 32),
    // ot = w>>2... (w>>1, 0..3). lane: l15 = row, quad = k-chunk.
    const int w    = __builtin_amdgcn_readfirstlane(tid >> 6);  // 0..7
    const int lane = tid & 63;
    const int l15  = lane & 15;
    const int quad = lane >> 4;
    const int rt   = w & 1;
    const int ot   = w >> 1;                                    // 0..3
    s16x8 av[2];
    #pragma unroll
    for (int ks = 0; ks < 2; ++ks)
        av[ks] = *(const s16x8*)&vsb[(rt * 16 + l15) * 64 + ks * 32 + quad * 8];

    #pragma unroll 1
    for (int kk = 0; kk < KNN; ++kk) {
        f32x4 ua = (f32x4){0.f, 0.f, 0.f, 0.f};
        #pragma unroll
        for (int ks = 0; ks < 2; ++ks) {
            s16x8 bw = *(const s16x8*)(cwb + ((((size_t)kk * 4 + ot) * 2 + ks) * 64 + lane) * 8);
            ua = __builtin_amdgcn_mfma_f32_16x16x32_bf16(av[ks], bw, ua, 0, 0, 0);
        }
        const size_t rowb = (size_t)(b * KNN + kk) * TT + tb * 32 + rt * 16 + quad * 4;
        #pragma unroll
        for (int r = 0; r < 4; ++r)
            ub[(rowb + r) * CH + ot * 16 + l15] = f2bf(ua[r]);
    }
}

// ---------------------------------------------------------------------------
// K2: FUSED sim + top-k + gather + conv (r16 win, untouched this round).
// ---------------------------------------------------------------------------
__global__ __launch_bounds__(256, 2) void sim_topk_kernel(
        const unsigned short* __restrict__ qtb, const unsigned short* __restrict__ ktb,
        const float* __restrict__ qtf, const float* __restrict__ ktf,
        const unsigned short* __restrict__ ub, const float* __restrict__ conv_b,
        float* __restrict__ out) {
    __shared__ int   cnt[64];
    __shared__ int   bkt[64 * SSTR];
    __shared__ float wbf[64 * SSTR];
    __shared__ int   sidx[64 * KNN];

    const int b    = blockIdx.x & 7;
    const int ib   = blockIdx.x >> 3;      // 0..63
    const int tid  = threadIdx.x;
    const int lane = tid & 63;
    const int w    = tid >> 6;             // wave 0..3
    const int w2r  = w >> 1;               // row half
    const int w2c  = w & 1;                // col half
    const int quad = lane >> 4;
    const int l15  = lane & 15;

    if (tid < 64) cnt[tid] = 0;
    __syncthreads();

    // k A-fragments in registers: rows w2r*32 + rt*16 + l15, k = quad*8+ks*32
    const unsigned short* kb = ktb + ((size_t)b * TT + ib * 64 + w2r * 32) * CH;
    s16x8 ka[2][2];
    #pragma unroll
    for (int rt = 0; rt < 2; ++rt)
        #pragma unroll
        for (int ks = 0; ks < 2; ++ks)
            ka[rt][ks] = *(const s16x8*)(kb + (size_t)(rt * 16 + l15) * CH + ks * 32 + quad * 8);

    // fragment-order q base for this batch & col-half:
    // frag[(b*256 + j0)*2 + ks][lane]*8, j0 = w2c*128 + jt*8 + jj
    const unsigned short* qfb = qtb + (((size_t)b * 256 + (size_t)w2c * 128) * 2) * 512
                                + (size_t)lane * 8;

    float s[2][4][2];
    #pragma unroll
    for (int rt = 0; rt < 2; ++rt)
        #pragma unroll
        for (int rg = 0; rg < 4; ++rg) { s[rt][rg][0] = NEG_INF; s[rt][rg][1] = NEG_INF; }

    // ------------------ PASS A: values-only top-2 (no barriers) ------------
    for (int jt = 0; jt < 16; ++jt) {
        const unsigned short* qrow = qfb + (size_t)(jt * 8) * 1024;  // j0 step=2*512
        s16x8 qf[8][2];
        #pragma unroll
        for (int jj = 0; jj < 8; ++jj)
            #pragma unroll
            for (int ks = 0; ks < 2; ++ks)
                qf[jj][ks] = *(const s16x8*)(qrow + (size_t)(jj * 2 + ks) * 512);

        f32x4 acc[2][8];
        #pragma unroll
        for (int rt = 0; rt < 2; ++rt)
            #pragma unroll
            for (int jj = 0; jj < 8; ++jj) acc[rt][jj] = (f32x4){0.f, 0.f, 0.f, 0.f};
        #pragma unroll
        for (int ks = 0; ks < 2; ++ks)
            #pragma unroll
            for (int rt = 0; rt < 2; ++rt)
                #pragma unroll
                for (int jj = 0; jj < 8; ++jj)
                    acc[rt][jj] = __builtin_amdgcn_mfma_f32_16x16x32_bf16(ka[rt][ks], qf[jj][ks], acc[rt][jj], 0, 0, 0);

        #pragma unroll
        for (int rt = 0; rt < 2; ++rt)
            #pragma unroll
            for (int jj = 0; jj < 8; ++jj) {
                insert2(acc[rt][jj][0], s[rt][0]);
                insert2(acc[rt][jj][1], s[rt][1]);
                insert2(acc[rt][jj][2], s[rt][2]);
                insert2(acc[rt][jj][3], s[rt][3]);
            }
    }

    // per-(row,half) θ — valid per half; no cross-wave merge needed
    float th[2][4];
    #pragma unroll
    for (int rt = 0; rt < 2; ++rt) {
        th[rt][0] = popTheta2(s[rt][0], lane);
        th[rt][1] = popTheta2(s[rt][1], lane);
        th[rt][2] = popTheta2(s[rt][2], lane);
        th[rt][3] = popTheta2(s[rt][3], lane);
    }

    // ------------------ PASS B: recompute (bitwise-identical) + collect ----
    for (int jt = 0; jt < 16; ++jt) {
        const unsigned short* qrow = qfb + (size_t)(jt * 8) * 1024;
        s16x8 qf[8][2];
        #pragma unroll
        for (int jj = 0; jj < 8; ++jj)
            #pragma unroll
            for (int ks = 0; ks < 2; ++ks)
                qf[jj][ks] = *(const s16x8*)(qrow + (size_t)(jj * 2 + ks) * 512);

        f32x4 acc[2][8];
        #pragma unroll
        for (int rt = 0; rt < 2; ++rt)
            #pragma unroll
            for (int jj = 0; jj < 8; ++jj) acc[rt][jj] = (f32x4){0.f, 0.f, 0.f, 0.f};
        #pragma unroll
        for (int ks = 0; ks < 2; ++ks)
            #pragma unroll
            for (int rt = 0; rt < 2; ++rt)
                #pragma unroll
                for (int jj = 0; jj < 8; ++jj)
                    acc[rt][jj] = __builtin_amdgcn_mfma_f32_16x16x32_bf16(ka[rt][ks], qf[jj][ks], acc[rt][jj], 0, 0, 0);

        #pragma unroll
        for (int rt = 0; rt < 2; ++rt)
            #pragma unroll
            for (int jj = 0; jj < 8; ++jj) {
                const int j = w2c * 2048 + jt * 128 + jj * 16 + l15;
                #pragma unroll
                for (int rg = 0; rg < 4; ++rg) {
                    if (acc[rt][jj][rg] >= th[rt][rg]) {
                        int rowl = w2r * 32 + rt * 16 + quad * 4 + rg;
                        int sl = atomicAdd(&cnt[rowl], 1);
                        if (sl < SLOTS) bkt[rowl * SSTR + sl] = j;
                    }
                }
            }
    }
    __syncthreads();

    // ------------------ exact fp32 rescore (L2-hot q/k fp32) ---------------
    {
        int r = tid >> 2, sub = tid & 3;
        int n = min(cnt[r], SLOTS);
        const float* krow = ktf + ((size_t)b * TT + ib * 64 + r) * CH;
        for (int m = sub; m < n; m += 4) {
            int j = bkt[r * SSTR + m];
            const float* qrow = qtf + ((size_t)b * TT + j) * CH;
            float wv = 0.f;
            #pragma unroll
            for (int c4 = 0; c4 < 16; ++c4) {
                float4 kv = *(const float4*)&krow[c4 * 4];
                float4 qv = *(const float4*)&qrow[c4 * 4];
                wv = fmaf(kv.x, qv.x, wv); wv = fmaf(kv.y, qv.y, wv);
                wv = fmaf(kv.z, qv.z, wv); wv = fmaf(kv.w, qv.w, wv);
            }
            wbf[r * SSTR + m] = wv;
        }
    }
    __syncthreads();

    if (tid < 64) {
        int n = min(cnt[tid], SLOTS);
        float s9[9]; int si9[9];
        #pragma unroll
        for (int k = 0; k < 9; ++k) { s9[k] = NEG_INF; si9[k] = 0x7fffffff; }
        #pragma unroll 1
        for (int m = 0; m < n; ++m) insert9x(wbf[tid * SSTR + m], bkt[tid * SSTR + m], s9, si9);
        #pragma unroll
        for (int m = 0; m < 9; ++m) sidx[tid * KNN + m] = si9[8 - m];
    }
    __syncthreads();

    // ------------------ fused gather + 1x1 conv ----------------------------
    {
        const int tl = tid & 63;
        const int og = tid >> 6;
        const int o0 = og * 16;

        float acc[16];
        #pragma unroll
        for (int q = 0; q < 16; ++q) acc[q] = conv_b[o0 + q];

        #pragma unroll
        for (int kk = 0; kk < KNN; ++kk) {
            int j = sidx[tl * KNN + kk];
            const unsigned short* up = ub + (((size_t)(b * KNN + kk)) * TT + j) * CH + o0;
            #pragma unroll
            for (int q8 = 0; q8 < 2; ++q8) {
                uint4 raw = *(const uint4*)&up[q8 * 8];
                unsigned rw[4] = {raw.x, raw.y, raw.z, raw.w};
                #pragma unroll
                for (int p = 0; p < 4; ++p) {
                    acc[q8 * 8 + 2 * p]     += __uint_as_float(rw[p] << 16);
                    acc[q8 * 8 + 2 * p + 1] += __uint_as_float(rw[p] & 0xFFFF0000u);
                }
            }
        }
        const int t = ib * 64 + tl;
        #pragma unroll
        for (int q = 0; q < 16; ++q)
            out[((size_t)b * CH + o0 + q) * TT + t] = acc[q];
    }
}

// ---------------------------------------------------------------------------
extern "C" void kernel_launch(void* const* d_in, const int* in_sizes, int n_in,
                              void* d_out, int out_size, void* d_ws, size_t ws_size,
                              hipStream_t stream) {
    const float* x   = (const float*)d_in[0];
    const float* Wq  = (const float*)d_in[1];
    const float* Wk  = (const float*)d_in[2];
    const float* Wv  = (const float*)d_in[3];
    const float* cw  = (const float*)d_in[4];
    const float* cbp = (const float*)d_in[5];

    float* ws = (float*)d_ws;
    unsigned short* ub  = (unsigned short*)(ws + OFF_UB);
    float* qtf          = ws + OFF_QTF;
    float* ktf          = ws + OFF_KTF;
    unsigned short* qtb = (unsigned short*)(ws + OFF_QTB);
    unsigned short* ktb = (unsigned short*)(ws + OFF_KTB);
    unsigned short* cwb = (unsigned short*)(ws + OFF_CWP);
    float* out          = (float*)d_out;

    repack_cw_kernel<<<(KNN * 4 * 2 * 64 + 255) / 256, 256, 0, stream>>>(cw, cwb);
    qkvu_kernel<<<BB * 128, 512, 0, stream>>>(x, Wq, Wk, Wv, cwb, qtf, ktf, qtb, ktb, ub);
    sim_topk_kernel<<<BB * 64, 256, 0, stream>>>(qtb, ktb, qtf, ktf, ub, cbp, out);
}